// Round 1
// baseline (2019.208 us; speedup 1.0000x reference)
//
#include <hip/hip_runtime.h>
#include <math.h>

#define N_ROWS  65536
#define EDIM    256
#define NE      1024
#define BETA    0.25f
#define LAMBDA  0.99f

// ---------------- ws layout (float units) ----------------
// [0]        loss accumulator
// [64]       e_sq[1024]       (numpy-exact fp32 row sums of emb*emb)
// [2048]     zsq[65536]       (numpy-exact fp32 row sums of z*z)
// [67584]    b_hi[1024*256]   (bf16 emb, ushort, 131072 float slots)
// [264192]   idx[65536] (int)
// [329728]   counts[1024]

// out layout (float units): loss, z_q_st, idx, perplexity, N_t, m_t
#define O_ZQ   1
#define O_IDX  16777217
#define O_PERP 16842753
#define O_NT   16842754
#define O_MT   16843778

typedef __attribute__((ext_vector_type(8))) short short8;
typedef __attribute__((ext_vector_type(4))) float f32x4;

// RNE float -> bf16 (no NaN in this data)
__device__ __forceinline__ unsigned short f2bf(float f) {
    unsigned u = __float_as_uint(f);
    return (unsigned short)((u + 0x7fffu + ((u >> 16) & 1u)) >> 16);
}

// margin: worst-case |d_hh - d_exact| <= 2*||z||*||e||*2^-8 ~ 2.4e-3 (C-S bound),
// margin 8e-3 gives >2x headroom on the 2-sided bound + reorder slop.
#define MARGIN 8e-3f

// ---------------------------------------------------------------------------
// prep_b: emb -> bf16 b_hi[col][k] row-major; zero loss accumulator
__global__ __launch_bounds__(64) void prep_b_kernel(const float* __restrict__ emb,
                                                    unsigned short* __restrict__ b_hi,
                                                    float* __restrict__ loss_acc) {
    int j = blockIdx.x;          // code id
    int l = threadIdx.x;         // 0..63
    float4 v = ((const float4*)(emb + (size_t)j * EDIM))[l];
    unsigned a0 = (unsigned)f2bf(v.x) | ((unsigned)f2bf(v.y) << 16);
    unsigned a1 = (unsigned)f2bf(v.z) | ((unsigned)f2bf(v.w) << 16);
    ((uint2*)(b_hi + (size_t)j * EDIM))[l] = make_uint2(a0, a1);
    if (j == 0 && l == 0) *loss_acc = 0.0f;
}

// ---------------------------------------------------------------------------
// sq_kernel (emb): numpy-pairwise-exact fp32 sum of squares — UNCHANGED
// (feeds the exact-refine d formula; must stay bit-identical).
__global__ __launch_bounds__(256) void sq_kernel(const float* __restrict__ src,
                                                 float* __restrict__ dst) {
    const int tid = threadIdx.x;
    const int grp = tid >> 4;          // 16 rows per block
    const int q   = tid & 15;
    const int row = blockIdx.x * 16 + grp;
    const int h = q >> 3, j = q & 7;
    const float* __restrict__ p = src + (size_t)row * EDIM + h * 128 + j;
    float acc = __fmul_rn(p[0], p[0]);
    #pragma unroll
    for (int t = 1; t < 16; ++t) {
        float v = p[8 * t];
        acc = __fadd_rn(acc, __fmul_rn(v, v));
    }
    acc = __fadd_rn(acc, __shfl_xor(acc, 1));
    acc = __fadd_rn(acc, __shfl_xor(acc, 2));
    acc = __fadd_rn(acc, __shfl_xor(acc, 4));
    acc = __fadd_rn(acc, __shfl_xor(acc, 8));
    if (q == 0) dst[row] = acc;
}

// ---------------------------------------------------------------------------
// prep_z: coalesced LDS stage of z rows, then the SAME exact zsq tree as the
// old in-dist zsq (bit-identical dataflow per row).
__global__ __launch_bounds__(256) void prep_z_kernel(const float* __restrict__ z,
                                                     float* __restrict__ zsq) {
    __shared__ __align__(16) float a_lds[16 * EDIM];
    const int tid = threadIdx.x;
    const int row0 = blockIdx.x * 16;
    {
        const float4* __restrict__ src = (const float4*)(z + (size_t)row0 * EDIM);
        float4* dst = (float4*)a_lds;
        #pragma unroll
        for (int i = 0; i < 4; ++i) dst[tid + 256 * i] = src[tid + 256 * i];
    }
    __syncthreads();
    const int row = tid >> 4, q = tid & 15, h = q >> 3, j = q & 7;
    const float* p = a_lds + row * EDIM + h * 128 + j;
    float acc = __fmul_rn(p[0], p[0]);
    #pragma unroll
    for (int t = 1; t < 16; ++t) {
        float v = p[8 * t];
        acc = __fadd_rn(acc, __fmul_rn(v, v));
    }
    acc = __fadd_rn(acc, __shfl_xor(acc, 1));
    acc = __fadd_rn(acc, __shfl_xor(acc, 2));
    acc = __fadd_rn(acc, __shfl_xor(acc, 4));
    acc = __fadd_rn(acc, __shfl_xor(acc, 8));
    if (q == 0) zsq[row0 + row] = acc;
}

// ---------------------------------------------------------------------------
// argmin_kernel: bf16-hi MFMA filter over all 1024 codes + exact fp32 refine.
//  - 256 rows/block, 8 waves x 32 rows (2 row-tiles), grid = 256 (1/CU).
//  - A (z rows) converted to bf16 in VGPRs once; B chunk (64 cols x K) staged
//    in XOR-swizzled LDS (2-way max conflicts = free); 1 ds_read_b128 -> 2 MFMA.
//  - running per-row min of t = e_sq[col] - 2*acc; any col within MARGIN of
//    the running min (superset of final candidate set) is re-evaluated with
//    the EXACT fp32 chain of the previous kernel (same fma order, same zsq /
//    e_sq trees, same d formula, tie -> lowest idx) => argmin bit-identical.
__global__ __launch_bounds__(512) void argmin_kernel(const float* __restrict__ z,
                                                     const float* __restrict__ emb,
                                                     const unsigned short* __restrict__ b_hi,
                                                     const float* __restrict__ e_sq,
                                                     const float* __restrict__ zsq,
                                                     int* __restrict__ idx_out,
                                                     float* __restrict__ out_zq,
                                                     float* __restrict__ out_idx,
                                                     float* __restrict__ loss_acc) {
    __shared__ __align__(16) unsigned short Bs[64 * EDIM];  // 32 KB, swizzled
    __shared__ unsigned long long best_s[256];
    __shared__ int idx_s[256];
    __shared__ float lred[8];

    const int tid  = threadIdx.x;
    const int wid  = tid >> 6, lane = tid & 63;
    const int l15  = lane & 15, lg = lane >> 4;
    const int row0 = blockIdx.x * 256;
    const int rbase = row0 + wid * 32;

    if (tid < 256) best_s[tid] = ~0ull;

    // ---- A fragments: 2 row-tiles x 8 k-steps, bf16 in regs (64 VGPR) ----
    short8 a[2][8];
    #pragma unroll
    for (int rt = 0; rt < 2; ++rt) {
        #pragma unroll
        for (int ks = 0; ks < 8; ++ks) {
            const float* zp = z + (size_t)(rbase + rt * 16 + l15) * EDIM + ks * 32 + lg * 8;
            float4 f0 = *(const float4*)zp;
            float4 f1 = *(const float4*)(zp + 4);
            union { short8 s; unsigned short u[8]; } pk;
            pk.u[0] = f2bf(f0.x); pk.u[1] = f2bf(f0.y); pk.u[2] = f2bf(f0.z); pk.u[3] = f2bf(f0.w);
            pk.u[4] = f2bf(f1.x); pk.u[5] = f2bf(f1.y); pk.u[6] = f2bf(f1.z); pk.u[7] = f2bf(f1.w);
            a[rt][ks] = pk.s;
        }
    }

    float rm[2][4];
    #pragma unroll
    for (int rt = 0; rt < 2; ++rt)
        #pragma unroll
        for (int r = 0; r < 4; ++r) rm[rt][r] = 1e30f;

    const int sc = tid >> 3;   // staging col 0..63
    const int sk = tid & 7;

    for (int ch = 0; ch < 16; ++ch) {
        const int cb = ch * 64;
        __syncthreads();
        // ---- stage B chunk: coalesced global read, swizzled LDS write ----
        {
            const float4* src = (const float4*)(b_hi + (size_t)(cb + sc) * EDIM);
            float4* dstv = (float4*)Bs;
            #pragma unroll
            for (int i = 0; i < 4; ++i) {
                int kc = sk + i * 8;                       // 16B chunk index 0..31
                dstv[sc * 32 + (kc ^ (sc & 7))] = src[kc];
            }
        }
        __syncthreads();

        // ---- MFMA: 4 col-tiles x 8 k-steps, B frag reused across 2 row-tiles
        f32x4 acc[2][4];
        #pragma unroll
        for (int rt = 0; rt < 2; ++rt)
            #pragma unroll
            for (int ct = 0; ct < 4; ++ct) acc[rt][ct] = (f32x4){0.f, 0.f, 0.f, 0.f};

        const short8* Bv = (const short8*)Bs;
        #pragma unroll
        for (int ct = 0; ct < 4; ++ct) {
            const int col = ct * 16 + l15;
            #pragma unroll
            for (int ks = 0; ks < 8; ++ks) {
                int kc = ks * 4 + lg;
                short8 b = Bv[col * 32 + (kc ^ (col & 7))];
                acc[0][ct] = __builtin_amdgcn_mfma_f32_16x16x32_bf16(a[0][ks], b, acc[0][ct], 0, 0, 0);
                acc[1][ct] = __builtin_amdgcn_mfma_f32_16x16x32_bf16(a[1][ks], b, acc[1][ct], 0, 0, 0);
            }
        }

        float eqs[4];
        #pragma unroll
        for (int ct = 0; ct < 4; ++ct) eqs[ct] = e_sq[cb + ct * 16 + l15];

        // ---- update running row-min (includes this chunk) ----
        #pragma unroll
        for (int rt = 0; rt < 2; ++rt) {
            #pragma unroll
            for (int r = 0; r < 4; ++r) {
                float m = __fsub_rn(eqs[0], __fmul_rn(2.0f, acc[rt][0][r]));
                #pragma unroll
                for (int ct = 1; ct < 4; ++ct) {
                    float t = __fsub_rn(eqs[ct], __fmul_rn(2.0f, acc[rt][ct][r]));
                    m = fminf(m, t);
                }
                m = fminf(m, __shfl_xor(m, 1));
                m = fminf(m, __shfl_xor(m, 2));
                m = fminf(m, __shfl_xor(m, 4));
                m = fminf(m, __shfl_xor(m, 8));
                rm[rt][r] = fminf(rm[rt][r], m);
            }
        }

        // ---- candidate test + exact fp32 refine (rare, divergent) ----
        #pragma unroll
        for (int rt = 0; rt < 2; ++rt) {
            #pragma unroll
            for (int ct = 0; ct < 4; ++ct) {
                #pragma unroll
                for (int r = 0; r < 4; ++r) {
                    float t = __fsub_rn(eqs[ct], __fmul_rn(2.0f, acc[rt][ct][r]));
                    if (t <= rm[rt][r] + MARGIN) {
                        const int rl  = wid * 32 + rt * 16 + lg * 4 + r;
                        const int row = row0 + rl;
                        const int col = cb + ct * 16 + l15;
                        // exact chain: k-ascending fma, identical to old dist_kernel
                        const float4* zr = (const float4*)(z + (size_t)row * EDIM);
                        const float4* er = (const float4*)(emb + (size_t)col * EDIM);
                        float ae = 0.f;
                        #pragma unroll 4
                        for (int q = 0; q < 64; ++q) {
                            float4 x = zr[q], y = er[q];
                            ae = __fmaf_rn(x.x, y.x, ae);
                            ae = __fmaf_rn(x.y, y.y, ae);
                            ae = __fmaf_rn(x.z, y.z, ae);
                            ae = __fmaf_rn(x.w, y.w, ae);
                        }
                        float d = __fsub_rn(__fadd_rn(zsq[row], e_sq[col]), __fmul_rn(2.0f, ae));
                        unsigned u = __float_as_uint(d);
                        u = (u & 0x80000000u) ? ~u : (u | 0x80000000u);   // order-preserving
                        unsigned long long key = ((unsigned long long)u << 32) | (unsigned)col;
                        atomicMin(&best_s[rl], key);
                    }
                }
            }
        }
    }

    __syncthreads();
    if (tid < 256) {
        unsigned long long k = best_s[tid];
        int id = (int)(k & 0xffffffffull);
        idx_out[row0 + tid] = id;
        out_idx[row0 + tid] = (float)id;
        idx_s[tid] = id;
    }
    __syncthreads();

    // ---- z_q gather + store + loss (one row per wave per iter, coalesced) ----
    float lp = 0.f;
    const float4* z4 = (const float4*)z;
    const float4* e4 = (const float4*)emb;
    for (int i = 0; i < 32; ++i) {
        int flat = tid + i * 512;
        int r = flat >> 6, c4 = flat & 63;
        int id = idx_s[r];
        float4 e  = e4[(size_t)id * 64 + c4];
        float4 zv = z4[(size_t)(row0 + r) * 64 + c4];
        float* o = out_zq + (size_t)(row0 + r) * EDIM + c4 * 4;  // base odd-float: scalar stores
        o[0] = e.x; o[1] = e.y; o[2] = e.z; o[3] = e.w;
        float dx = e.x - zv.x, dy = e.y - zv.y, dz = e.z - zv.z, dw = e.w - zv.w;
        lp += dx * dx + dy * dy + dz * dz + dw * dw;
    }
    #pragma unroll
    for (int m = 32; m; m >>= 1) lp += __shfl_down(lp, m);
    if (lane == 0) lred[wid] = lp;
    __syncthreads();
    if (tid == 0) {
        float s = lred[0] + lred[1] + lred[2] + lred[3]
                + lred[4] + lred[5] + lred[6] + lred[7];
        atomicAdd(loss_acc, s);
    }
}

// ---------------------------------------------------------------------------
// stats: one block per code, 1024 threads (16 waves) — UNCHANGED
#define CHUNK 8192
__global__ __launch_bounds__(1024) void stats_kernel(const float* __restrict__ z,
                                                     const int* __restrict__ idx,
                                                     const float* __restrict__ N_t,
                                                     const float* __restrict__ m_t,
                                                     float* __restrict__ outN,
                                                     float* __restrict__ outM,
                                                     float* __restrict__ counts) {
    const int j = blockIdx.x;
    __shared__ int list[CHUNK];        // 32 KB
    __shared__ int cnt_s;
    __shared__ float red[16 * 256];    // 16 KB
    const int tid = threadIdx.x, w = tid >> 6, lane = tid & 63;
    float4 acc = make_float4(0.f, 0.f, 0.f, 0.f);
    int total = 0;
    for (int c = 0; c < N_ROWS; c += CHUNK) {
        if (tid == 0) cnt_s = 0;
        __syncthreads();
        #pragma unroll
        for (int i = 0; i < CHUNK / 1024; ++i) {
            int p = c + tid + i * 1024;
            if (idx[p] == j) { int s = atomicAdd(&cnt_s, 1); list[s] = p; }
        }
        __syncthreads();
        int m = cnt_s;
        total += m;
        for (int e = w; e < m; e += 16) {
            float4 v = ((const float4*)(z + (size_t)list[e] * EDIM))[lane];
            acc.x += v.x; acc.y += v.y; acc.z += v.z; acc.w += v.w;
        }
        __syncthreads();
    }
    *(float4*)(red + w * 256 + lane * 4) = acc;
    __syncthreads();
    if (tid < 256) {
        float s = 0.f;
        #pragma unroll
        for (int ww = 0; ww < 16; ++ww) s += red[ww * 256 + tid];
        float mold = m_t[(size_t)j * EDIM + tid];
        outM[(size_t)j * EDIM + tid] = (total > 0) ? mold * LAMBDA + s * (1.0f - LAMBDA) : mold;
    }
    if (tid == 0) {
        float Nold = N_t[j];
        outN[j] = (total > 0) ? Nold * LAMBDA + (float)total * (1.0f - LAMBDA) : Nold;
        counts[j] = (float)total;
    }
}

// ---------------------------------------------------------------------------
// finalize: loss scale + perplexity from counts — UNCHANGED
__global__ __launch_bounds__(256) void final_kernel(const float* __restrict__ counts,
                                                    const float* __restrict__ loss_acc,
                                                    float* __restrict__ out_loss,
                                                    float* __restrict__ out_perp) {
    const int tid = threadIdx.x, w = tid >> 6, lane = tid & 63;
    float h = 0.f;
    for (int c = tid; c < NE; c += 256) {
        float em = counts[c] * (1.0f / (float)N_ROWS);
        h += em * logf(em + 1e-10f);
    }
    #pragma unroll
    for (int m = 32; m; m >>= 1) h += __shfl_down(h, m);
    __shared__ float red[4];
    if (lane == 0) red[w] = h;
    __syncthreads();
    if (tid == 0) {
        float H = red[0] + red[1] + red[2] + red[3];
        out_perp[0] = expf(-H);
        out_loss[0] = BETA * loss_acc[0] * (1.0f / (float)(N_ROWS * EDIM));
    }
}

// ---------------------------------------------------------------------------
extern "C" void kernel_launch(void* const* d_in, const int* in_sizes, int n_in,
                              void* d_out, int out_size, void* d_ws, size_t ws_size,
                              hipStream_t stream) {
    const float* z   = (const float*)d_in[0];
    const float* emb = (const float*)d_in[1];
    const float* N_t = (const float*)d_in[2];
    const float* m_t = (const float*)d_in[3];
    float* out = (float*)d_out;
    float* ws  = (float*)d_ws;

    float* loss_acc      = ws;
    float* e_sq          = ws + 64;
    float* zsq           = ws + 2048;
    unsigned short* b_hi = (unsigned short*)(ws + 67584);
    int*   idx1          = (int*)(ws + 264192);
    float* counts        = ws + 329728;

    prep_b_kernel<<<NE, 64, 0, stream>>>(emb, b_hi, loss_acc);
    sq_kernel<<<NE / 16, 256, 0, stream>>>(emb, e_sq);
    prep_z_kernel<<<N_ROWS / 16, 256, 0, stream>>>(z, zsq);
    argmin_kernel<<<N_ROWS / 256, 512, 0, stream>>>(z, emb, b_hi, e_sq, zsq, idx1,
                                                    out + O_ZQ, out + O_IDX, loss_acc);
    stats_kernel<<<NE, 1024, 0, stream>>>(z, idx1, N_t, m_t, out + O_NT, out + O_MT, counts);
    final_kernel<<<1, 256, 0, stream>>>(counts, loss_acc, out, out + O_PERP);
}

// Round 2
// 435.743 us; speedup vs baseline: 4.6339x; 4.6339x over previous
//
#include <hip/hip_runtime.h>
#include <math.h>

#define N_ROWS  65536
#define EDIM    256
#define NE      1024
#define BETA    0.25f
#define LAMBDA  0.99f

// margin: worst-case two-sided bf16-filter error bound is 4.8e-3
// (2 * 2^-7 * ||z||*||e|| per side, Cauchy-Schwarz); 8e-3 = verified-passing.
#define MARGIN  8e-3f
#define QCAP    4096

// ---------------- ws layout (float units) ----------------
// [0]        loss accumulator
// [64]       e_sq[1024]       (numpy-exact fp32 row sums of emb*emb)
// [2048]     zsq[65536]       (numpy-exact fp32 row sums of z*z)
// [67584]    b_frag           (bf16 emb in MFMA fragment order, 512 KB)
// [264192]   idx[65536] (int)
// [329728]   counts[1024]

// out layout (float units): loss, z_q_st, idx, perplexity, N_t, m_t
#define O_ZQ   1
#define O_IDX  16777217
#define O_PERP 16842753
#define O_NT   16842754
#define O_MT   16843778

typedef __attribute__((ext_vector_type(8))) short short8;
typedef __attribute__((ext_vector_type(4))) float f32x4;

// RNE float -> bf16 (no NaN in this data)
__device__ __forceinline__ unsigned short f2bf(float f) {
    unsigned u = __float_as_uint(f);
    return (unsigned short)((u + 0x7fffu + ((u >> 16) & 1u)) >> 16);
}

// ---------------------------------------------------------------------------
// prep_b: emb -> bf16 in MFMA B-fragment order.
// Fragment entry (16B = short8) index: (ctg*8 + ks)*64 + lane, holding
// B[k = ks*32 + lg*8 .. +7][col = ctg*16 + l15]  (lane = lg*16 + l15).
// Thread l of block j covers k = 4l..4l+3 of col j -> two u32 at
// entry ((j>>4)*8 + (l>>3)), lane ((l>>1)&3)*16 + (j&15), u32 slot 2*(l&1).
__global__ __launch_bounds__(64) void prep_b_kernel(const float* __restrict__ emb,
                                                    unsigned* __restrict__ bfrag_u32,
                                                    float* __restrict__ loss_acc) {
    int j = blockIdx.x;          // code id (column)
    int l = threadIdx.x;         // 0..63
    float4 v = ((const float4*)(emb + (size_t)j * EDIM))[l];
    unsigned lo = (unsigned)f2bf(v.x) | ((unsigned)f2bf(v.y) << 16);
    unsigned hi = (unsigned)f2bf(v.z) | ((unsigned)f2bf(v.w) << 16);
    int base = ((((j >> 4) * 8 + (l >> 3)) * 64) + ((l >> 1) & 3) * 16 + (j & 15)) * 4
             + 2 * (l & 1);
    bfrag_u32[base]     = lo;
    bfrag_u32[base + 1] = hi;
    if (j == 0 && l == 0) *loss_acc = 0.0f;
}

// ---------------------------------------------------------------------------
// sq_kernel (emb): numpy-pairwise-exact fp32 sum of squares — UNCHANGED
__global__ __launch_bounds__(256) void sq_kernel(const float* __restrict__ src,
                                                 float* __restrict__ dst) {
    const int tid = threadIdx.x;
    const int grp = tid >> 4;          // 16 rows per block
    const int q   = tid & 15;
    const int row = blockIdx.x * 16 + grp;
    const int h = q >> 3, j = q & 7;
    const float* __restrict__ p = src + (size_t)row * EDIM + h * 128 + j;
    float acc = __fmul_rn(p[0], p[0]);
    #pragma unroll
    for (int t = 1; t < 16; ++t) {
        float v = p[8 * t];
        acc = __fadd_rn(acc, __fmul_rn(v, v));
    }
    acc = __fadd_rn(acc, __shfl_xor(acc, 1));
    acc = __fadd_rn(acc, __shfl_xor(acc, 2));
    acc = __fadd_rn(acc, __shfl_xor(acc, 4));
    acc = __fadd_rn(acc, __shfl_xor(acc, 8));
    if (q == 0) dst[row] = acc;
}

// ---------------------------------------------------------------------------
// prep_z: coalesced LDS stage of z rows, exact zsq tree — UNCHANGED
__global__ __launch_bounds__(256) void prep_z_kernel(const float* __restrict__ z,
                                                     float* __restrict__ zsq) {
    __shared__ __align__(16) float a_lds[16 * EDIM];
    const int tid = threadIdx.x;
    const int row0 = blockIdx.x * 16;
    {
        const float4* __restrict__ src = (const float4*)(z + (size_t)row0 * EDIM);
        float4* dst = (float4*)a_lds;
        #pragma unroll
        for (int i = 0; i < 4; ++i) dst[tid + 256 * i] = src[tid + 256 * i];
    }
    __syncthreads();
    const int row = tid >> 4, q = tid & 15, h = q >> 3, j = q & 7;
    const float* p = a_lds + row * EDIM + h * 128 + j;
    float acc = __fmul_rn(p[0], p[0]);
    #pragma unroll
    for (int t = 1; t < 16; ++t) {
        float v = p[8 * t];
        acc = __fadd_rn(acc, __fmul_rn(v, v));
    }
    acc = __fadd_rn(acc, __shfl_xor(acc, 1));
    acc = __fadd_rn(acc, __shfl_xor(acc, 2));
    acc = __fadd_rn(acc, __shfl_xor(acc, 4));
    acc = __fadd_rn(acc, __shfl_xor(acc, 8));
    if (q == 0) zsq[row0 + row] = acc;
}

// ---------------------------------------------------------------------------
// argmin_kernel v2: barrier-free MFMA main loop (B direct from L2 in fragment
// order), deferred cooperative exact refine via LDS candidate queue.
//  - 256 rows/block, 8 waves x 32 rows (2 row-tiles), grid = 256.
//  - Filter: t = e_sq[col] - 2*(bf16 z.e); running per-row min; cols within
//    MARGIN of running min are ENQUEUED (not refined inline).
//  - Refine: 16 lanes per candidate, fixed split-k fp32 dot + shfl tree,
//    d = (zsq + e_sq) - 2*ae on the same fp32 grid as the reference;
//    packed-key LDS atomicMin, lowest idx on ties (matches argmin-first).
__global__ __launch_bounds__(512, 2) void argmin_kernel(const float* __restrict__ z,
                                                        const float* __restrict__ emb,
                                                        const short8* __restrict__ bfrag,
                                                        const float* __restrict__ e_sq,
                                                        const float* __restrict__ zsq,
                                                        int* __restrict__ idx_out,
                                                        float* __restrict__ out_zq,
                                                        float* __restrict__ out_idx,
                                                        float* __restrict__ loss_acc) {
    __shared__ unsigned long long best_s[256];   // 2 KB
    __shared__ int queue[QCAP];                  // 16 KB
    __shared__ int qcnt;
    __shared__ int idx_s[256];
    __shared__ float lred[8];

    const int tid  = threadIdx.x;
    const int wid  = tid >> 6, lane = tid & 63;
    const int l15  = lane & 15, lg = lane >> 4;
    const int row0 = blockIdx.x * 256;
    const int rbase = row0 + wid * 32;

    if (tid < 256) best_s[tid] = ~0ull;
    if (tid == 0) qcnt = 0;

    // ---- A fragments: 2 row-tiles x 8 k-steps, bf16 in regs (64 VGPR) ----
    short8 a[2][8];
    #pragma unroll
    for (int rt = 0; rt < 2; ++rt) {
        #pragma unroll
        for (int ks = 0; ks < 8; ++ks) {
            const float* zp = z + (size_t)(rbase + rt * 16 + l15) * EDIM + ks * 32 + lg * 8;
            float4 f0 = *(const float4*)zp;
            float4 f1 = *(const float4*)(zp + 4);
            union { short8 s; unsigned short u[8]; } pk;
            pk.u[0] = f2bf(f0.x); pk.u[1] = f2bf(f0.y); pk.u[2] = f2bf(f0.z); pk.u[3] = f2bf(f0.w);
            pk.u[4] = f2bf(f1.x); pk.u[5] = f2bf(f1.y); pk.u[6] = f2bf(f1.z); pk.u[7] = f2bf(f1.w);
            a[rt][ks] = pk.s;
        }
    }

    float rm[2][4];
    #pragma unroll
    for (int rt = 0; rt < 2; ++rt)
        #pragma unroll
        for (int r = 0; r < 4; ++r) rm[rt][r] = 1e30f;

    __syncthreads();   // qcnt / best_s init visible

    // ---- main loop: no barriers, B straight from L2 (fragment-ordered) ----
    for (int ch = 0; ch < 16; ++ch) {
        const int cb = ch * 64;
        f32x4 acc[2][4];
        #pragma unroll
        for (int rt = 0; rt < 2; ++rt)
            #pragma unroll
            for (int ct = 0; ct < 4; ++ct) acc[rt][ct] = (f32x4){0.f, 0.f, 0.f, 0.f};

        #pragma unroll
        for (int ks = 0; ks < 8; ++ks) {
            #pragma unroll
            for (int ct = 0; ct < 4; ++ct) {
                short8 b = bfrag[(size_t)((ch * 4 + ct) * 8 + ks) * 64 + lane]; // coalesced 1KB/wave
                acc[0][ct] = __builtin_amdgcn_mfma_f32_16x16x32_bf16(a[0][ks], b, acc[0][ct], 0, 0, 0);
                acc[1][ct] = __builtin_amdgcn_mfma_f32_16x16x32_bf16(a[1][ks], b, acc[1][ct], 0, 0, 0);
            }
        }

        float eqs[4];
        #pragma unroll
        for (int ct = 0; ct < 4; ++ct) eqs[ct] = e_sq[cb + ct * 16 + l15];

        // ---- running row-min (includes this chunk) ----
        #pragma unroll
        for (int rt = 0; rt < 2; ++rt) {
            #pragma unroll
            for (int r = 0; r < 4; ++r) {
                float m = __fsub_rn(eqs[0], __fmul_rn(2.0f, acc[rt][0][r]));
                #pragma unroll
                for (int ct = 1; ct < 4; ++ct) {
                    float t = __fsub_rn(eqs[ct], __fmul_rn(2.0f, acc[rt][ct][r]));
                    m = fminf(m, t);
                }
                m = fminf(m, __shfl_xor(m, 1));
                m = fminf(m, __shfl_xor(m, 2));
                m = fminf(m, __shfl_xor(m, 4));
                m = fminf(m, __shfl_xor(m, 8));
                rm[rt][r] = fminf(rm[rt][r], m);
            }
        }

        // ---- enqueue candidates (cheap; refine deferred) ----
        #pragma unroll
        for (int rt = 0; rt < 2; ++rt) {
            #pragma unroll
            for (int ct = 0; ct < 4; ++ct) {
                #pragma unroll
                for (int r = 0; r < 4; ++r) {
                    float t = __fsub_rn(eqs[ct], __fmul_rn(2.0f, acc[rt][ct][r]));
                    if (t <= rm[rt][r] + MARGIN) {
                        int rl  = wid * 32 + rt * 16 + lg * 4 + r;
                        int col = cb + ct * 16 + l15;
                        int s = atomicAdd(&qcnt, 1);
                        if (s < QCAP) queue[s] = (rl << 10) | col;
                    }
                }
            }
        }
    }

    __syncthreads();

    // ---- cooperative exact refine: 16 lanes per candidate ----
    {
        int nq = qcnt; if (nq > QCAP) nq = QCAP;
        const int g = tid >> 4, q = tid & 15;
        for (int e = g; e < nq; e += 32) {
            int ent = queue[e];
            int rl = ent >> 10, col = ent & 1023;
            const float4* zr = (const float4*)(z + (size_t)(row0 + rl) * EDIM) + q * 4;
            const float4* er = (const float4*)(emb + (size_t)col * EDIM) + q * 4;
            float ae = 0.f;
            #pragma unroll
            for (int i = 0; i < 4; ++i) {
                float4 x = zr[i], y = er[i];
                ae = __fmaf_rn(x.x, y.x, ae);
                ae = __fmaf_rn(x.y, y.y, ae);
                ae = __fmaf_rn(x.z, y.z, ae);
                ae = __fmaf_rn(x.w, y.w, ae);
            }
            ae = __fadd_rn(ae, __shfl_xor(ae, 1));
            ae = __fadd_rn(ae, __shfl_xor(ae, 2));
            ae = __fadd_rn(ae, __shfl_xor(ae, 4));
            ae = __fadd_rn(ae, __shfl_xor(ae, 8));
            if (q == 0) {
                float d = __fsub_rn(__fadd_rn(zsq[row0 + rl], e_sq[col]), __fmul_rn(2.0f, ae));
                unsigned u = __float_as_uint(d);
                u = (u & 0x80000000u) ? ~u : (u | 0x80000000u);   // order-preserving map
                unsigned long long key = ((unsigned long long)u << 32) | (unsigned)col;
                atomicMin(&best_s[rl], key);
            }
        }
    }

    __syncthreads();
    if (tid < 256) {
        unsigned long long k = best_s[tid];
        int id = (int)(k & 0xffffffffull);
        idx_out[row0 + tid] = id;
        out_idx[row0 + tid] = (float)id;
        idx_s[tid] = id;
    }
    __syncthreads();

    // ---- z_q gather + store + loss ----
    float lp = 0.f;
    const float4* z4 = (const float4*)z;
    const float4* e4 = (const float4*)emb;
    for (int i = 0; i < 32; ++i) {
        int flat = tid + i * 512;
        int r = flat >> 6, c4 = flat & 63;
        int id = idx_s[r];
        float4 e  = e4[(size_t)id * 64 + c4];
        float4 zv = z4[(size_t)(row0 + r) * 64 + c4];
        float* o = out_zq + (size_t)(row0 + r) * EDIM + c4 * 4;  // base odd-float: scalar stores
        o[0] = e.x; o[1] = e.y; o[2] = e.z; o[3] = e.w;
        float dx = e.x - zv.x, dy = e.y - zv.y, dz = e.z - zv.z, dw = e.w - zv.w;
        lp += dx * dx + dy * dy + dz * dz + dw * dw;
    }
    #pragma unroll
    for (int m = 32; m; m >>= 1) lp += __shfl_down(lp, m);
    if (lane == 0) lred[wid] = lp;
    __syncthreads();
    if (tid == 0) {
        float s = lred[0] + lred[1] + lred[2] + lred[3]
                + lred[4] + lred[5] + lred[6] + lred[7];
        atomicAdd(loss_acc, s);
    }
}

// ---------------------------------------------------------------------------
// stats: one block per code, 1024 threads (16 waves) — UNCHANGED
#define CHUNK 8192
__global__ __launch_bounds__(1024) void stats_kernel(const float* __restrict__ z,
                                                     const int* __restrict__ idx,
                                                     const float* __restrict__ N_t,
                                                     const float* __restrict__ m_t,
                                                     float* __restrict__ outN,
                                                     float* __restrict__ outM,
                                                     float* __restrict__ counts) {
    const int j = blockIdx.x;
    __shared__ int list[CHUNK];        // 32 KB
    __shared__ int cnt_s;
    __shared__ float red[16 * 256];    // 16 KB
    const int tid = threadIdx.x, w = tid >> 6, lane = tid & 63;
    float4 acc = make_float4(0.f, 0.f, 0.f, 0.f);
    int total = 0;
    for (int c = 0; c < N_ROWS; c += CHUNK) {
        if (tid == 0) cnt_s = 0;
        __syncthreads();
        #pragma unroll
        for (int i = 0; i < CHUNK / 1024; ++i) {
            int p = c + tid + i * 1024;
            if (idx[p] == j) { int s = atomicAdd(&cnt_s, 1); list[s] = p; }
        }
        __syncthreads();
        int m = cnt_s;
        total += m;
        for (int e = w; e < m; e += 16) {
            float4 v = ((const float4*)(z + (size_t)list[e] * EDIM))[lane];
            acc.x += v.x; acc.y += v.y; acc.z += v.z; acc.w += v.w;
        }
        __syncthreads();
    }
    *(float4*)(red + w * 256 + lane * 4) = acc;
    __syncthreads();
    if (tid < 256) {
        float s = 0.f;
        #pragma unroll
        for (int ww = 0; ww < 16; ++ww) s += red[ww * 256 + tid];
        float mold = m_t[(size_t)j * EDIM + tid];
        outM[(size_t)j * EDIM + tid] = (total > 0) ? mold * LAMBDA + s * (1.0f - LAMBDA) : mold;
    }
    if (tid == 0) {
        float Nold = N_t[j];
        outN[j] = (total > 0) ? Nold * LAMBDA + (float)total * (1.0f - LAMBDA) : Nold;
        counts[j] = (float)total;
    }
}

// ---------------------------------------------------------------------------
// finalize — UNCHANGED
__global__ __launch_bounds__(256) void final_kernel(const float* __restrict__ counts,
                                                    const float* __restrict__ loss_acc,
                                                    float* __restrict__ out_loss,
                                                    float* __restrict__ out_perp) {
    const int tid = threadIdx.x, w = tid >> 6, lane = tid & 63;
    float h = 0.f;
    for (int c = tid; c < NE; c += 256) {
        float em = counts[c] * (1.0f / (float)N_ROWS);
        h += em * logf(em + 1e-10f);
    }
    #pragma unroll
    for (int m = 32; m; m >>= 1) h += __shfl_down(h, m);
    __shared__ float red[4];
    if (lane == 0) red[w] = h;
    __syncthreads();
    if (tid == 0) {
        float H = red[0] + red[1] + red[2] + red[3];
        out_perp[0] = expf(-H);
        out_loss[0] = BETA * loss_acc[0] * (1.0f / (float)(N_ROWS * EDIM));
    }
}

// ---------------------------------------------------------------------------
extern "C" void kernel_launch(void* const* d_in, const int* in_sizes, int n_in,
                              void* d_out, int out_size, void* d_ws, size_t ws_size,
                              hipStream_t stream) {
    const float* z   = (const float*)d_in[0];
    const float* emb = (const float*)d_in[1];
    const float* N_t = (const float*)d_in[2];
    const float* m_t = (const float*)d_in[3];
    float* out = (float*)d_out;
    float* ws  = (float*)d_ws;

    float* loss_acc   = ws;
    float* e_sq       = ws + 64;
    float* zsq        = ws + 2048;
    unsigned* bfrag_u = (unsigned*)(ws + 67584);
    int*   idx1       = (int*)(ws + 264192);
    float* counts     = ws + 329728;

    prep_b_kernel<<<NE, 64, 0, stream>>>(emb, bfrag_u, loss_acc);
    sq_kernel<<<NE / 16, 256, 0, stream>>>(emb, e_sq);
    prep_z_kernel<<<N_ROWS / 16, 256, 0, stream>>>(z, zsq);
    argmin_kernel<<<N_ROWS / 256, 512, 0, stream>>>(z, emb, (const short8*)bfrag_u,
                                                    e_sq, zsq, idx1,
                                                    out + O_ZQ, out + O_IDX, loss_acc);
    stats_kernel<<<NE, 1024, 0, stream>>>(z, idx1, N_t, m_t, out + O_NT, out + O_MT, counts);
    final_kernel<<<1, 256, 0, stream>>>(counts, loss_acc, out, out + O_PERP);
}

// Round 3
// 366.234 us; speedup vs baseline: 5.5134x; 1.1898x over previous
//
#include <hip/hip_runtime.h>
#include <math.h>

#define N_ROWS  65536
#define EDIM    256
#define NE      1024
#define BETA    0.25f
#define LAMBDA  0.99f

// margin: worst-case two-sided bf16-filter error bound is 4.8e-3
// (2 * 2^-7 * ||z||*||e|| per side, Cauchy-Schwarz); 8e-3 = verified-passing.
#define MARGIN  8e-3f
#define QCAP    8192

// ---------------- ws layout (float units) ----------------
// [0]        loss accumulator
// [64]       e_sq[1024]       (numpy-exact fp32 row sums of emb*emb)
// [2048]     zsq[65536]       (numpy-exact fp32 row sums of z*z)
// [67584]    b_frag           (bf16 emb in MFMA fragment order, 512 KB)
// [198656]   sorted[65536]    (int; row ids grouped by code — dead-gap reuse)
// [264192]   idx[65536] (int)
// [329728]   counts[1024]     (float, for final_kernel)
// [330752]   cnt_i[1024]      (int histogram)
// [331776]   offs_i[1024]     (int exclusive prefix)
// [332800]   cursor_i[1024]   (int scatter cursors)

// out layout (float units): loss, z_q_st, idx, perplexity, N_t, m_t
#define O_ZQ   1
#define O_IDX  16777217
#define O_PERP 16842753
#define O_NT   16842754
#define O_MT   16843778

typedef __attribute__((ext_vector_type(8))) short short8;
typedef __attribute__((ext_vector_type(4))) float f32x4;

// RNE float -> bf16 (no NaN in this data)
__device__ __forceinline__ unsigned short f2bf(float f) {
    unsigned u = __float_as_uint(f);
    return (unsigned short)((u + 0x7fffu + ((u >> 16) & 1u)) >> 16);
}

// ---------------------------------------------------------------------------
// prep_b: emb -> bf16 in MFMA B-fragment order; zero loss + histogram.
// Fragment entry (16B = short8) index: (ctg*8 + ks)*64 + lane, holding
// B[k = ks*32 + lg*8 .. +7][col = ctg*16 + l15]  (lane = lg*16 + l15).
__global__ __launch_bounds__(64) void prep_b_kernel(const float* __restrict__ emb,
                                                    unsigned* __restrict__ bfrag_u32,
                                                    float* __restrict__ loss_acc,
                                                    int* __restrict__ cnt) {
    int j = blockIdx.x;          // code id (column)
    int l = threadIdx.x;         // 0..63
    float4 v = ((const float4*)(emb + (size_t)j * EDIM))[l];
    unsigned lo = (unsigned)f2bf(v.x) | ((unsigned)f2bf(v.y) << 16);
    unsigned hi = (unsigned)f2bf(v.z) | ((unsigned)f2bf(v.w) << 16);
    int base = ((((j >> 4) * 8 + (l >> 3)) * 64) + ((l >> 1) & 3) * 16 + (j & 15)) * 4
             + 2 * (l & 1);
    bfrag_u32[base]     = lo;
    bfrag_u32[base + 1] = hi;
    if (l == 0) cnt[j] = 0;
    if (j == 0 && l == 0) *loss_acc = 0.0f;
}

// ---------------------------------------------------------------------------
// sq_kernel (emb): numpy-pairwise-exact fp32 sum of squares — UNCHANGED
__global__ __launch_bounds__(256) void sq_kernel(const float* __restrict__ src,
                                                 float* __restrict__ dst) {
    const int tid = threadIdx.x;
    const int grp = tid >> 4;          // 16 rows per block
    const int q   = tid & 15;
    const int row = blockIdx.x * 16 + grp;
    const int h = q >> 3, j = q & 7;
    const float* __restrict__ p = src + (size_t)row * EDIM + h * 128 + j;
    float acc = __fmul_rn(p[0], p[0]);
    #pragma unroll
    for (int t = 1; t < 16; ++t) {
        float v = p[8 * t];
        acc = __fadd_rn(acc, __fmul_rn(v, v));
    }
    acc = __fadd_rn(acc, __shfl_xor(acc, 1));
    acc = __fadd_rn(acc, __shfl_xor(acc, 2));
    acc = __fadd_rn(acc, __shfl_xor(acc, 4));
    acc = __fadd_rn(acc, __shfl_xor(acc, 8));
    if (q == 0) dst[row] = acc;
}

// ---------------------------------------------------------------------------
// prep_z: coalesced LDS stage of z rows, exact zsq tree — UNCHANGED
__global__ __launch_bounds__(256) void prep_z_kernel(const float* __restrict__ z,
                                                     float* __restrict__ zsq) {
    __shared__ __align__(16) float a_lds[16 * EDIM];
    const int tid = threadIdx.x;
    const int row0 = blockIdx.x * 16;
    {
        const float4* __restrict__ src = (const float4*)(z + (size_t)row0 * EDIM);
        float4* dst = (float4*)a_lds;
        #pragma unroll
        for (int i = 0; i < 4; ++i) dst[tid + 256 * i] = src[tid + 256 * i];
    }
    __syncthreads();
    const int row = tid >> 4, q = tid & 15, h = q >> 3, j = q & 7;
    const float* p = a_lds + row * EDIM + h * 128 + j;
    float acc = __fmul_rn(p[0], p[0]);
    #pragma unroll
    for (int t = 1; t < 16; ++t) {
        float v = p[8 * t];
        acc = __fadd_rn(acc, __fmul_rn(v, v));
    }
    acc = __fadd_rn(acc, __shfl_xor(acc, 1));
    acc = __fadd_rn(acc, __shfl_xor(acc, 2));
    acc = __fadd_rn(acc, __shfl_xor(acc, 4));
    acc = __fadd_rn(acc, __shfl_xor(acc, 8));
    if (q == 0) zsq[row0 + row] = acc;
}

// ---------------------------------------------------------------------------
// argmin_kernel v3: LDS-staged B with register prefetch one chunk ahead
// (latency hidden structurally), deferred 8-lane-group exact refine,
// loss decoded from the winning refined d (no epilogue z re-read).
__global__ __launch_bounds__(512, 2) void argmin_kernel(const float* __restrict__ z,
                                                        const float* __restrict__ emb,
                                                        const float4* __restrict__ bsrc,
                                                        const float* __restrict__ e_sq,
                                                        const float* __restrict__ zsq,
                                                        int* __restrict__ idx_out,
                                                        float* __restrict__ out_zq,
                                                        float* __restrict__ out_idx,
                                                        float* __restrict__ loss_acc) {
    __shared__ __align__(16) float4 Bs[2048];    // 32 KB, one B chunk (64 cols x K)
    __shared__ unsigned long long best_s[256];   // 2 KB
    __shared__ int queue[QCAP];                  // 32 KB
    __shared__ int qcnt;
    __shared__ int idx_s[256];
    __shared__ float lred[8];

    const int tid  = threadIdx.x;
    const int wid  = tid >> 6, lane = tid & 63;
    const int l15  = lane & 15, lg = lane >> 4;
    const int row0 = blockIdx.x * 256;
    const int rbase = row0 + wid * 32;

    if (tid < 256) best_s[tid] = ~0ull;
    if (tid == 0) qcnt = 0;

    // ---- issue chunk-0 B prefetch first (lands under the A-phase) ----
    float4 st[4];
    #pragma unroll
    for (int i = 0; i < 4; ++i) st[i] = bsrc[tid + 512 * i];

    // ---- A fragments: 2 row-tiles x 8 k-steps, bf16 in regs (64 VGPR) ----
    short8 a[2][8];
    #pragma unroll
    for (int rt = 0; rt < 2; ++rt) {
        #pragma unroll
        for (int ks = 0; ks < 8; ++ks) {
            const float* zp = z + (size_t)(rbase + rt * 16 + l15) * EDIM + ks * 32 + lg * 8;
            float4 f0 = *(const float4*)zp;
            float4 f1 = *(const float4*)(zp + 4);
            union { short8 s; unsigned short u[8]; } pk;
            pk.u[0] = f2bf(f0.x); pk.u[1] = f2bf(f0.y); pk.u[2] = f2bf(f0.z); pk.u[3] = f2bf(f0.w);
            pk.u[4] = f2bf(f1.x); pk.u[5] = f2bf(f1.y); pk.u[6] = f2bf(f1.z); pk.u[7] = f2bf(f1.w);
            a[rt][ks] = pk.s;
        }
    }

    float rm[2][4];
    #pragma unroll
    for (int rt = 0; rt < 2; ++rt)
        #pragma unroll
        for (int r = 0; r < 4; ++r) rm[rt][r] = 1e30f;

    __syncthreads();   // qcnt / best_s init visible

    // ---- main loop: ds_write staged chunk -> barrier -> prefetch next ->
    //      MFMA from LDS -> filter/enqueue -> barrier ----
    for (int ch = 0; ch < 16; ++ch) {
        const int cb = ch * 64;
        #pragma unroll
        for (int i = 0; i < 4; ++i) Bs[tid + 512 * i] = st[i];
        __syncthreads();
        if (ch < 15) {
            #pragma unroll
            for (int i = 0; i < 4; ++i) st[i] = bsrc[(ch + 1) * 2048 + tid + 512 * i];
        }

        float eqs[4];
        #pragma unroll
        for (int ct = 0; ct < 4; ++ct) eqs[ct] = e_sq[cb + ct * 16 + l15];

        f32x4 acc[2][4];
        #pragma unroll
        for (int rt = 0; rt < 2; ++rt)
            #pragma unroll
            for (int ct = 0; ct < 4; ++ct) acc[rt][ct] = (f32x4){0.f, 0.f, 0.f, 0.f};

        const short8* Bv = (const short8*)Bs;
        #pragma unroll
        for (int ks = 0; ks < 8; ++ks) {     // ks outer: 8 independent chains back-to-back
            #pragma unroll
            for (int ct = 0; ct < 4; ++ct) {
                short8 b = Bv[(ct * 8 + ks) * 64 + lane];   // conflict-free ds_read_b128
                acc[0][ct] = __builtin_amdgcn_mfma_f32_16x16x32_bf16(a[0][ks], b, acc[0][ct], 0, 0, 0);
                acc[1][ct] = __builtin_amdgcn_mfma_f32_16x16x32_bf16(a[1][ks], b, acc[1][ct], 0, 0, 0);
            }
        }

        // ---- running row-min (includes this chunk) ----
        #pragma unroll
        for (int rt = 0; rt < 2; ++rt) {
            #pragma unroll
            for (int r = 0; r < 4; ++r) {
                float m = __fsub_rn(eqs[0], __fmul_rn(2.0f, acc[rt][0][r]));
                #pragma unroll
                for (int ct = 1; ct < 4; ++ct) {
                    float t = __fsub_rn(eqs[ct], __fmul_rn(2.0f, acc[rt][ct][r]));
                    m = fminf(m, t);
                }
                m = fminf(m, __shfl_xor(m, 1));
                m = fminf(m, __shfl_xor(m, 2));
                m = fminf(m, __shfl_xor(m, 4));
                m = fminf(m, __shfl_xor(m, 8));
                rm[rt][r] = fminf(rm[rt][r], m);
            }
        }

        // ---- enqueue candidates (refine deferred) ----
        #pragma unroll
        for (int rt = 0; rt < 2; ++rt) {
            #pragma unroll
            for (int ct = 0; ct < 4; ++ct) {
                #pragma unroll
                for (int r = 0; r < 4; ++r) {
                    float t = __fsub_rn(eqs[ct], __fmul_rn(2.0f, acc[rt][ct][r]));
                    if (t <= rm[rt][r] + MARGIN) {
                        int rl  = wid * 32 + rt * 16 + lg * 4 + r;
                        int col = cb + ct * 16 + l15;
                        int s = atomicAdd(&qcnt, 1);
                        if (s < QCAP) queue[s] = (rl << 10) | col;
                    }
                }
            }
        }
        __syncthreads();   // all waves done reading Bs before next ds_write
    }

    __syncthreads();

    // ---- cooperative exact refine: 8 lanes per candidate (64 groups) ----
    {
        int nq = qcnt; if (nq > QCAP) nq = QCAP;
        const int g = tid >> 3, q = tid & 7;
        for (int e = g; e < nq; e += 64) {
            int ent = queue[e];
            int rl = ent >> 10, col = ent & 1023;
            const float4* zr = (const float4*)(z + (size_t)(row0 + rl) * EDIM);
            const float4* er = (const float4*)(emb + (size_t)col * EDIM);
            float ae = 0.f;
            #pragma unroll
            for (int i = 0; i < 8; ++i) {
                float4 x = zr[q + 8 * i], y = er[q + 8 * i];
                ae = __fmaf_rn(x.x, y.x, ae);
                ae = __fmaf_rn(x.y, y.y, ae);
                ae = __fmaf_rn(x.z, y.z, ae);
                ae = __fmaf_rn(x.w, y.w, ae);
            }
            ae = __fadd_rn(ae, __shfl_xor(ae, 1));
            ae = __fadd_rn(ae, __shfl_xor(ae, 2));
            ae = __fadd_rn(ae, __shfl_xor(ae, 4));
            if (q == 0) {
                float d = __fsub_rn(__fadd_rn(zsq[row0 + rl], e_sq[col]), __fmul_rn(2.0f, ae));
                unsigned u = __float_as_uint(d);
                u = (u & 0x80000000u) ? ~u : (u | 0x80000000u);   // order-preserving map
                unsigned long long key = ((unsigned long long)u << 32) | (unsigned)col;
                atomicMin(&best_s[rl], key);
            }
        }
    }

    __syncthreads();
    if (tid < 256) {
        unsigned long long k = best_s[tid];
        int id = (int)(k & 0xffffffffull);
        idx_out[row0 + tid] = id;
        out_idx[row0 + tid] = (float)id;
        idx_s[tid] = id;
    }
    __syncthreads();

    // ---- z_q gather + store (emb rows only) ----
    const float4* e4 = (const float4*)emb;
    for (int i = 0; i < 32; ++i) {
        int flat = tid + i * 512;
        int r = flat >> 6, c4 = flat & 63;
        int id = idx_s[r];
        float4 e = e4[(size_t)id * 64 + c4];
        float* o = out_zq + (size_t)(row0 + r) * EDIM + c4 * 4;  // base odd-float: scalar stores
        o[0] = e.x; o[1] = e.y; o[2] = e.z; o[3] = e.w;
    }

    // ---- loss: decode the winning refined d per row, reduce, accumulate ----
    float lp = 0.f;
    if (tid < 256) {
        unsigned m = (unsigned)(best_s[tid] >> 32);
        unsigned bits = (m & 0x80000000u) ? (m & 0x7fffffffu) : ~m;
        lp = __uint_as_float(bits);
    }
    #pragma unroll
    for (int m = 32; m; m >>= 1) lp += __shfl_down(lp, m);
    if (lane == 0) lred[wid] = lp;
    __syncthreads();
    if (tid == 0) {
        float s = lred[0] + lred[1] + lred[2] + lred[3]
                + lred[4] + lred[5] + lred[6] + lred[7];
        atomicAdd(loss_acc, s);
    }
}

// ---------------------------------------------------------------------------
// stats via counting sort: hist -> scan (offsets, N_t, counts) -> scatter -> msum
__global__ __launch_bounds__(256) void hist_kernel(const int* __restrict__ idx,
                                                   int* __restrict__ cnt) {
    int i = blockIdx.x * 256 + threadIdx.x;
    atomicAdd(&cnt[idx[i]], 1);
}

__global__ __launch_bounds__(1024) void scan_kernel(const int* __restrict__ cnt,
                                                    const float* __restrict__ N_t,
                                                    float* __restrict__ outN,
                                                    float* __restrict__ counts_f,
                                                    int* __restrict__ offs,
                                                    int* __restrict__ cursor) {
    __shared__ int s[1024];
    const int tid = threadIdx.x;
    int c = cnt[tid];
    s[tid] = c;
    __syncthreads();
    for (int d = 1; d < 1024; d <<= 1) {
        int v = (tid >= d) ? s[tid - d] : 0;
        __syncthreads();
        s[tid] += v;
        __syncthreads();
    }
    int excl = s[tid] - c;
    offs[tid] = excl;
    cursor[tid] = excl;
    counts_f[tid] = (float)c;
    float Nold = N_t[tid];
    outN[tid] = (c > 0) ? Nold * LAMBDA + (float)c * (1.0f - LAMBDA) : Nold;
}

__global__ __launch_bounds__(256) void scatter_kernel(const int* __restrict__ idx,
                                                      int* __restrict__ cursor,
                                                      int* __restrict__ sorted) {
    int i = blockIdx.x * 256 + threadIdx.x;
    int p = atomicAdd(&cursor[idx[i]], 1);
    sorted[p] = i;
}

__global__ __launch_bounds__(256) void msum_kernel(const float* __restrict__ z,
                                                   const int* __restrict__ sorted,
                                                   const int* __restrict__ offs,
                                                   const int* __restrict__ cnt,
                                                   const float* __restrict__ m_t,
                                                   float* __restrict__ outM) {
    const int j = blockIdx.x;
    const int tid = threadIdx.x, w = tid >> 6, lane = tid & 63;
    const int n = cnt[j], start = offs[j];
    float4 acc = make_float4(0.f, 0.f, 0.f, 0.f);
    for (int e = w; e < n; e += 4) {
        float4 v = ((const float4*)(z + (size_t)sorted[start + e] * EDIM))[lane];
        acc.x += v.x; acc.y += v.y; acc.z += v.z; acc.w += v.w;
    }
    __shared__ float red[4 * 256];
    *(float4*)(red + w * 256 + lane * 4) = acc;
    __syncthreads();
    if (tid < 256) {
        float s = red[tid] + red[256 + tid] + red[512 + tid] + red[768 + tid];
        float mold = m_t[(size_t)j * EDIM + tid];
        outM[(size_t)j * EDIM + tid] = (n > 0) ? mold * LAMBDA + s * (1.0f - LAMBDA) : mold;
    }
}

// ---------------------------------------------------------------------------
// finalize — UNCHANGED
__global__ __launch_bounds__(256) void final_kernel(const float* __restrict__ counts,
                                                    const float* __restrict__ loss_acc,
                                                    float* __restrict__ out_loss,
                                                    float* __restrict__ out_perp) {
    const int tid = threadIdx.x, w = tid >> 6, lane = tid & 63;
    float h = 0.f;
    for (int c = tid; c < NE; c += 256) {
        float em = counts[c] * (1.0f / (float)N_ROWS);
        h += em * logf(em + 1e-10f);
    }
    #pragma unroll
    for (int m = 32; m; m >>= 1) h += __shfl_down(h, m);
    __shared__ float red[4];
    if (lane == 0) red[w] = h;
    __syncthreads();
    if (tid == 0) {
        float H = red[0] + red[1] + red[2] + red[3];
        out_perp[0] = expf(-H);
        out_loss[0] = BETA * loss_acc[0] * (1.0f / (float)(N_ROWS * EDIM));
    }
}

// ---------------------------------------------------------------------------
extern "C" void kernel_launch(void* const* d_in, const int* in_sizes, int n_in,
                              void* d_out, int out_size, void* d_ws, size_t ws_size,
                              hipStream_t stream) {
    const float* z   = (const float*)d_in[0];
    const float* emb = (const float*)d_in[1];
    const float* N_t = (const float*)d_in[2];
    const float* m_t = (const float*)d_in[3];
    float* out = (float*)d_out;
    float* ws  = (float*)d_ws;

    float* loss_acc   = ws;
    float* e_sq       = ws + 64;
    float* zsq        = ws + 2048;
    unsigned* bfrag_u = (unsigned*)(ws + 67584);
    int*   sorted     = (int*)(ws + 198656);
    int*   idx1       = (int*)(ws + 264192);
    float* counts     = ws + 329728;
    int*   cnt_i      = (int*)(ws + 330752);
    int*   offs_i     = (int*)(ws + 331776);
    int*   cursor_i   = (int*)(ws + 332800);

    prep_b_kernel<<<NE, 64, 0, stream>>>(emb, bfrag_u, loss_acc, cnt_i);
    sq_kernel<<<NE / 16, 256, 0, stream>>>(emb, e_sq);
    prep_z_kernel<<<N_ROWS / 16, 256, 0, stream>>>(z, zsq);
    argmin_kernel<<<N_ROWS / 256, 512, 0, stream>>>(z, emb, (const float4*)bfrag_u,
                                                    e_sq, zsq, idx1,
                                                    out + O_ZQ, out + O_IDX, loss_acc);
    hist_kernel<<<N_ROWS / 256, 256, 0, stream>>>(idx1, cnt_i);
    scan_kernel<<<1, 1024, 0, stream>>>(cnt_i, N_t, out + O_NT, counts, offs_i, cursor_i);
    scatter_kernel<<<N_ROWS / 256, 256, 0, stream>>>(idx1, cursor_i, sorted);
    msum_kernel<<<NE, 256, 0, stream>>>(z, sorted, offs_i, cnt_i, m_t, out + O_MT);
    final_kernel<<<1, 256, 0, stream>>>(counts, loss_acc, out, out + O_PERP);
}

// Round 4
// 342.551 us; speedup vs baseline: 5.8946x; 1.0691x over previous
//
#include <hip/hip_runtime.h>
#include <math.h>

#define N_ROWS  65536
#define EDIM    256
#define NE      1024
#define BETA    0.25f
#define LAMBDA  0.99f

// margin: worst-case two-sided bf16-filter error bound is 4.8e-3
// (2 * 2^-7 * ||z||*||e|| per side, Cauchy-Schwarz); 8e-3 = verified-passing.
#define MARGIN  8e-3f
#define QCAP    2048

// ---------------- ws layout (float units) ----------------
// [0]        loss accumulator
// [64]       e_sq[1024]       (numpy-exact fp32 row sums of emb*emb)
// [67584]    b_frag           (bf16 emb in MFMA fragment order, 512 KB)
// [198656]   sorted[65536]    (int; row ids grouped by code)
// [264192]   idx[65536] (int)
// [329728]   counts[1024]     (float, for final_kernel)
// [330752]   cnt_i[1024]      (int histogram — zeroed in prep_b, filled in argmin)
// [331776]   offs_i[1024]     (int exclusive prefix)
// [332800]   cursor_i[1024]   (int scatter cursors)

// out layout (float units): loss, z_q_st, idx, perplexity, N_t, m_t
#define O_ZQ   1
#define O_IDX  16777217
#define O_PERP 16842753
#define O_NT   16842754
#define O_MT   16843778

typedef __attribute__((ext_vector_type(8))) short short8;
typedef __attribute__((ext_vector_type(4))) float f32x4;

// RNE float -> bf16 (no NaN in this data)
__device__ __forceinline__ unsigned short f2bf(float f) {
    unsigned u = __float_as_uint(f);
    return (unsigned short)((u + 0x7fffu + ((u >> 16) & 1u)) >> 16);
}

// ---------------------------------------------------------------------------
// prep_b: emb -> bf16 in MFMA B-fragment order; zero loss + histogram.
// Fragment entry (16B = short8) index: (ctg*8 + ks)*64 + lane, holding
// B[k = ks*32 + lg*8 .. +7][col = ctg*16 + l15]  (lane = lg*16 + l15).
__global__ __launch_bounds__(64) void prep_b_kernel(const float* __restrict__ emb,
                                                    unsigned* __restrict__ bfrag_u32,
                                                    float* __restrict__ loss_acc,
                                                    int* __restrict__ cnt) {
    int j = blockIdx.x;          // code id (column)
    int l = threadIdx.x;         // 0..63
    float4 v = ((const float4*)(emb + (size_t)j * EDIM))[l];
    unsigned lo = (unsigned)f2bf(v.x) | ((unsigned)f2bf(v.y) << 16);
    unsigned hi = (unsigned)f2bf(v.z) | ((unsigned)f2bf(v.w) << 16);
    int base = ((((j >> 4) * 8 + (l >> 3)) * 64) + ((l >> 1) & 3) * 16 + (j & 15)) * 4
             + 2 * (l & 1);
    bfrag_u32[base]     = lo;
    bfrag_u32[base + 1] = hi;
    if (l == 0) cnt[j] = 0;
    if (j == 0 && l == 0) *loss_acc = 0.0f;
}

// ---------------------------------------------------------------------------
// sq_kernel (emb): numpy-pairwise-exact fp32 sum of squares — UNCHANGED
// (e_sq enters the cross-candidate exact-d comparison; keep the exact tree).
__global__ __launch_bounds__(256) void sq_kernel(const float* __restrict__ src,
                                                 float* __restrict__ dst) {
    const int tid = threadIdx.x;
    const int grp = tid >> 4;          // 16 rows per block
    const int q   = tid & 15;
    const int row = blockIdx.x * 16 + grp;
    const int h = q >> 3, j = q & 7;
    const float* __restrict__ p = src + (size_t)row * EDIM + h * 128 + j;
    float acc = __fmul_rn(p[0], p[0]);
    #pragma unroll
    for (int t = 1; t < 16; ++t) {
        float v = p[8 * t];
        acc = __fadd_rn(acc, __fmul_rn(v, v));
    }
    acc = __fadd_rn(acc, __shfl_xor(acc, 1));
    acc = __fadd_rn(acc, __shfl_xor(acc, 2));
    acc = __fadd_rn(acc, __shfl_xor(acc, 4));
    acc = __fadd_rn(acc, __shfl_xor(acc, 8));
    if (q == 0) dst[row] = acc;
}

// ---------------------------------------------------------------------------
// argmin_kernel v4: 128 rows/block, 256 threads, grid 512 -> 3 blocks/CU
// (LDS 51.7 KB). t-carrying queue with post-filter against the FINAL row min
// (~8x fewer refine gathers, bit-identical winner). zsq computed in-register
// from the A-phase loads (additive per-row constant -> argmin invariant);
// histogram fused into the idx writeback.
__global__ __launch_bounds__(256, 3) void argmin_kernel(const float* __restrict__ z,
                                                        const float* __restrict__ emb,
                                                        const float4* __restrict__ bsrc,
                                                        const float* __restrict__ e_sq,
                                                        int* __restrict__ idx_out,
                                                        float* __restrict__ out_zq,
                                                        float* __restrict__ out_idx,
                                                        float* __restrict__ loss_acc,
                                                        int* __restrict__ cnt) {
    __shared__ __align__(16) float4 Bs[2048];    // 32 KB, one B chunk (64 cols x K)
    __shared__ uint2 queue[QCAP];                // 16 KB  (packed rl|col, t-bits)
    __shared__ unsigned long long best_s[128];   // 1 KB
    __shared__ int   idx_s[128];
    __shared__ float zsq_s[128];
    __shared__ float rmF_s[128];
    __shared__ float lred[4];
    __shared__ int qcnt;

    const int tid  = threadIdx.x;
    const int wid  = tid >> 6, lane = tid & 63;
    const int l15  = lane & 15, lg = lane >> 4;
    const int row0 = blockIdx.x * 128;
    const int rbase = row0 + wid * 32;

    if (tid < 128) best_s[tid] = ~0ull;
    if (tid == 0) qcnt = 0;

    // ---- issue chunk-0 B prefetch first (lands under the A-phase) ----
    float4 st[8];
    #pragma unroll
    for (int i = 0; i < 8; ++i) st[i] = bsrc[tid + 256 * i];

    // ---- A fragments: 2 row-tiles x 8 k-steps, bf16 in regs; zsq on the fly ----
    short8 a[2][8];
    #pragma unroll
    for (int rt = 0; rt < 2; ++rt) {
        float zs = 0.f;
        #pragma unroll
        for (int ks = 0; ks < 8; ++ks) {
            const float* zp = z + (size_t)(rbase + rt * 16 + l15) * EDIM + ks * 32 + lg * 8;
            float4 f0 = *(const float4*)zp;
            float4 f1 = *(const float4*)(zp + 4);
            zs += f0.x * f0.x + f0.y * f0.y + f0.z * f0.z + f0.w * f0.w
                + f1.x * f1.x + f1.y * f1.y + f1.z * f1.z + f1.w * f1.w;
            union { short8 s; unsigned short u[8]; } pk;
            pk.u[0] = f2bf(f0.x); pk.u[1] = f2bf(f0.y); pk.u[2] = f2bf(f0.z); pk.u[3] = f2bf(f0.w);
            pk.u[4] = f2bf(f1.x); pk.u[5] = f2bf(f1.y); pk.u[6] = f2bf(f1.z); pk.u[7] = f2bf(f1.w);
            a[rt][ks] = pk.s;
        }
        zs += __shfl_xor(zs, 16);        // combine lg groups (row-uniform constant;
        zs += __shfl_xor(zs, 32);        //  cancels in per-row argmin comparison)
        if (lg == 0) zsq_s[wid * 32 + rt * 16 + l15] = zs;
    }

    float rm[2][4];
    #pragma unroll
    for (int rt = 0; rt < 2; ++rt)
        #pragma unroll
        for (int r = 0; r < 4; ++r) rm[rt][r] = 1e30f;

    __syncthreads();   // qcnt / best_s init visible

    // ---- main loop: ds_write staged chunk -> barrier -> prefetch next ->
    //      MFMA from LDS -> filter/enqueue(t) -> barrier ----
    for (int ch = 0; ch < 16; ++ch) {
        const int cb = ch * 64;
        #pragma unroll
        for (int i = 0; i < 8; ++i) Bs[tid + 256 * i] = st[i];
        __syncthreads();
        if (ch < 15) {
            #pragma unroll
            for (int i = 0; i < 8; ++i) st[i] = bsrc[(ch + 1) * 2048 + tid + 256 * i];
        }

        float eqs[4];
        #pragma unroll
        for (int ct = 0; ct < 4; ++ct) eqs[ct] = e_sq[cb + ct * 16 + l15];

        f32x4 acc[2][4];
        #pragma unroll
        for (int rt = 0; rt < 2; ++rt)
            #pragma unroll
            for (int ct = 0; ct < 4; ++ct) acc[rt][ct] = (f32x4){0.f, 0.f, 0.f, 0.f};

        const short8* Bv = (const short8*)Bs;
        #pragma unroll
        for (int ks = 0; ks < 8; ++ks) {
            #pragma unroll
            for (int ct = 0; ct < 4; ++ct) {
                short8 b = Bv[(ct * 8 + ks) * 64 + lane];   // conflict-free ds_read_b128
                acc[0][ct] = __builtin_amdgcn_mfma_f32_16x16x32_bf16(a[0][ks], b, acc[0][ct], 0, 0, 0);
                acc[1][ct] = __builtin_amdgcn_mfma_f32_16x16x32_bf16(a[1][ks], b, acc[1][ct], 0, 0, 0);
            }
        }

        // ---- running row-min (includes this chunk) ----
        #pragma unroll
        for (int rt = 0; rt < 2; ++rt) {
            #pragma unroll
            for (int r = 0; r < 4; ++r) {
                float m = __fsub_rn(eqs[0], __fmul_rn(2.0f, acc[rt][0][r]));
                #pragma unroll
                for (int ct = 1; ct < 4; ++ct) {
                    float t = __fsub_rn(eqs[ct], __fmul_rn(2.0f, acc[rt][ct][r]));
                    m = fminf(m, t);
                }
                m = fminf(m, __shfl_xor(m, 1));
                m = fminf(m, __shfl_xor(m, 2));
                m = fminf(m, __shfl_xor(m, 4));
                m = fminf(m, __shfl_xor(m, 8));
                rm[rt][r] = fminf(rm[rt][r], m);
            }
        }

        // ---- enqueue candidates with their t (post-filtered before refine) ----
        #pragma unroll
        for (int rt = 0; rt < 2; ++rt) {
            #pragma unroll
            for (int ct = 0; ct < 4; ++ct) {
                #pragma unroll
                for (int r = 0; r < 4; ++r) {
                    float t = __fsub_rn(eqs[ct], __fmul_rn(2.0f, acc[rt][ct][r]));
                    if (t <= rm[rt][r] + MARGIN) {
                        int rl  = wid * 32 + rt * 16 + lg * 4 + r;
                        int col = cb + ct * 16 + l15;
                        int s = atomicAdd(&qcnt, 1);
                        if (s < QCAP) queue[s] = make_uint2((rl << 10) | col,
                                                            __float_as_uint(t));
                    }
                }
            }
        }
        __syncthreads();   // all waves done reading Bs before next ds_write
    }

    // ---- publish final per-row min for the post-filter ----
    #pragma unroll
    for (int rt = 0; rt < 2; ++rt)
        #pragma unroll
        for (int r = 0; r < 4; ++r)
            if (l15 == 0) rmF_s[wid * 32 + rt * 16 + lg * 4 + r] = rm[rt][r];
    __syncthreads();

    // ---- cooperative exact refine: 8 lanes per candidate, post-filtered ----
    {
        int nq = qcnt; if (nq > QCAP) nq = QCAP;
        const int g = tid >> 3, q = tid & 7;      // 32 groups
        for (int e = g; e < nq; e += 32) {
            uint2 ent = queue[e];
            int rl = ent.x >> 10, col = ent.x & 1023;
            if (__uint_as_float(ent.y) > rmF_s[rl] + MARGIN) continue;  // ~8x cull
            const float4* zr = (const float4*)(z + (size_t)(row0 + rl) * EDIM);
            const float4* er = (const float4*)(emb + (size_t)col * EDIM);
            float ae = 0.f;
            #pragma unroll
            for (int i = 0; i < 8; ++i) {
                float4 x = zr[q + 8 * i], y = er[q + 8 * i];
                ae = __fmaf_rn(x.x, y.x, ae);
                ae = __fmaf_rn(x.y, y.y, ae);
                ae = __fmaf_rn(x.z, y.z, ae);
                ae = __fmaf_rn(x.w, y.w, ae);
            }
            ae = __fadd_rn(ae, __shfl_xor(ae, 1));
            ae = __fadd_rn(ae, __shfl_xor(ae, 2));
            ae = __fadd_rn(ae, __shfl_xor(ae, 4));
            if (q == 0) {
                float d = __fsub_rn(__fadd_rn(zsq_s[rl], e_sq[col]), __fmul_rn(2.0f, ae));
                unsigned u = __float_as_uint(d);
                u = (u & 0x80000000u) ? ~u : (u | 0x80000000u);   // order-preserving map
                unsigned long long key = ((unsigned long long)u << 32) | (unsigned)col;
                atomicMin(&best_s[rl], key);
            }
        }
    }

    __syncthreads();
    if (tid < 128) {
        unsigned long long k = best_s[tid];
        int id = (int)(k & 0xffffffffull);
        idx_out[row0 + tid] = id;
        out_idx[row0 + tid] = (float)id;
        idx_s[tid] = id;
        atomicAdd(&cnt[id], 1);          // fused histogram
    }
    __syncthreads();

    // ---- z_q gather + store (emb rows only) ----
    const float4* e4 = (const float4*)emb;
    for (int i = 0; i < 32; ++i) {
        int flat = tid + i * 256;
        int r = flat >> 6, c4 = flat & 63;
        int id = idx_s[r];
        float4 e = e4[(size_t)id * 64 + c4];
        float* o = out_zq + (size_t)(row0 + r) * EDIM + c4 * 4;  // base odd-float: scalar stores
        o[0] = e.x; o[1] = e.y; o[2] = e.z; o[3] = e.w;
    }

    // ---- loss: decode the winning refined d per row, reduce, accumulate ----
    float lp = 0.f;
    if (tid < 128) {
        unsigned m = (unsigned)(best_s[tid] >> 32);
        unsigned bits = (m & 0x80000000u) ? (m & 0x7fffffffu) : ~m;
        lp = __uint_as_float(bits);
    }
    #pragma unroll
    for (int m = 32; m; m >>= 1) lp += __shfl_down(lp, m);
    if (lane == 0) lred[wid] = lp;
    __syncthreads();
    if (tid == 0) {
        float s = lred[0] + lred[1] + lred[2] + lred[3];
        atomicAdd(loss_acc, s);
    }
}

// ---------------------------------------------------------------------------
// stats via counting sort: scan (offsets, N_t, counts) -> scatter -> msum
__global__ __launch_bounds__(1024) void scan_kernel(const int* __restrict__ cnt,
                                                    const float* __restrict__ N_t,
                                                    float* __restrict__ outN,
                                                    float* __restrict__ counts_f,
                                                    int* __restrict__ offs,
                                                    int* __restrict__ cursor) {
    __shared__ int s[1024];
    const int tid = threadIdx.x;
    int c = cnt[tid];
    s[tid] = c;
    __syncthreads();
    for (int d = 1; d < 1024; d <<= 1) {
        int v = (tid >= d) ? s[tid - d] : 0;
        __syncthreads();
        s[tid] += v;
        __syncthreads();
    }
    int excl = s[tid] - c;
    offs[tid] = excl;
    cursor[tid] = excl;
    counts_f[tid] = (float)c;
    float Nold = N_t[tid];
    outN[tid] = (c > 0) ? Nold * LAMBDA + (float)c * (1.0f - LAMBDA) : Nold;
}

__global__ __launch_bounds__(256) void scatter_kernel(const int* __restrict__ idx,
                                                      int* __restrict__ cursor,
                                                      int* __restrict__ sorted) {
    int i = blockIdx.x * 256 + threadIdx.x;
    int p = atomicAdd(&cursor[idx[i]], 1);
    sorted[p] = i;
}

__global__ __launch_bounds__(256) void msum_kernel(const float* __restrict__ z,
                                                   const int* __restrict__ sorted,
                                                   const int* __restrict__ offs,
                                                   const int* __restrict__ cnt,
                                                   const float* __restrict__ m_t,
                                                   float* __restrict__ outM) {
    const int j = blockIdx.x;
    const int tid = threadIdx.x, w = tid >> 6, lane = tid & 63;
    const int n = cnt[j], start = offs[j];
    float4 acc = make_float4(0.f, 0.f, 0.f, 0.f);
    for (int e = w; e < n; e += 4) {
        float4 v = ((const float4*)(z + (size_t)sorted[start + e] * EDIM))[lane];
        acc.x += v.x; acc.y += v.y; acc.z += v.z; acc.w += v.w;
    }
    __shared__ float red[4 * 256];
    *(float4*)(red + w * 256 + lane * 4) = acc;
    __syncthreads();
    if (tid < 256) {
        float s = red[tid] + red[256 + tid] + red[512 + tid] + red[768 + tid];
        float mold = m_t[(size_t)j * EDIM + tid];
        outM[(size_t)j * EDIM + tid] = (n > 0) ? mold * LAMBDA + s * (1.0f - LAMBDA) : mold;
    }
}

// ---------------------------------------------------------------------------
// finalize — UNCHANGED
__global__ __launch_bounds__(256) void final_kernel(const float* __restrict__ counts,
                                                    const float* __restrict__ loss_acc,
                                                    float* __restrict__ out_loss,
                                                    float* __restrict__ out_perp) {
    const int tid = threadIdx.x, w = tid >> 6, lane = tid & 63;
    float h = 0.f;
    for (int c = tid; c < NE; c += 256) {
        float em = counts[c] * (1.0f / (float)N_ROWS);
        h += em * logf(em + 1e-10f);
    }
    #pragma unroll
    for (int m = 32; m; m >>= 1) h += __shfl_down(h, m);
    __shared__ float red[4];
    if (lane == 0) red[w] = h;
    __syncthreads();
    if (tid == 0) {
        float H = red[0] + red[1] + red[2] + red[3];
        out_perp[0] = expf(-H);
        out_loss[0] = BETA * loss_acc[0] * (1.0f / (float)(N_ROWS * EDIM));
    }
}

// ---------------------------------------------------------------------------
extern "C" void kernel_launch(void* const* d_in, const int* in_sizes, int n_in,
                              void* d_out, int out_size, void* d_ws, size_t ws_size,
                              hipStream_t stream) {
    const float* z   = (const float*)d_in[0];
    const float* emb = (const float*)d_in[1];
    const float* N_t = (const float*)d_in[2];
    const float* m_t = (const float*)d_in[3];
    float* out = (float*)d_out;
    float* ws  = (float*)d_ws;

    float* loss_acc   = ws;
    float* e_sq       = ws + 64;
    unsigned* bfrag_u = (unsigned*)(ws + 67584);
    int*   sorted     = (int*)(ws + 198656);
    int*   idx1       = (int*)(ws + 264192);
    float* counts     = ws + 329728;
    int*   cnt_i      = (int*)(ws + 330752);
    int*   offs_i     = (int*)(ws + 331776);
    int*   cursor_i   = (int*)(ws + 332800);

    prep_b_kernel<<<NE, 64, 0, stream>>>(emb, bfrag_u, loss_acc, cnt_i);
    sq_kernel<<<NE / 16, 256, 0, stream>>>(emb, e_sq);
    argmin_kernel<<<N_ROWS / 128, 256, 0, stream>>>(z, emb, (const float4*)bfrag_u,
                                                    e_sq, idx1,
                                                    out + O_ZQ, out + O_IDX, loss_acc, cnt_i);
    scan_kernel<<<1, 1024, 0, stream>>>(cnt_i, N_t, out + O_NT, counts, offs_i, cursor_i);
    scatter_kernel<<<N_ROWS / 256, 256, 0, stream>>>(idx1, cursor_i, sorted);
    msum_kernel<<<NE, 256, 0, stream>>>(z, sorted, offs_i, cnt_i, m_t, out + O_MT);
    final_kernel<<<1, 256, 0, stream>>>(counts, loss_acc, out, out + O_PERP);
}